// Round 11
// baseline (267.701 us; speedup 1.0000x reference)
//
#include <hip/hip_runtime.h>
#include <hip/hip_bf16.h>
#include <math.h>

typedef __hip_bfloat16 bf16;
typedef __attribute__((ext_vector_type(4))) float f32x4;
typedef __attribute__((ext_vector_type(8))) short s16x8;

#define NB 8192
#define KP 1152   // padded K: 1089 -> 18*64
#define NP 1152   // padded N: 1089 -> 8*144
#define NKT 18    // K-tiles of 64
#define SBLK 256  // stats blocks per subnet (32 rows each)

struct SubP {
    const float* x; const float* gamma; const float* beta;
    const float* W1; const float* b1; const float* W2; const float* b2;
    const float* W3; const float* b3;
    float* sum; float* sumsq; float* a; float* b1p; float* hout;
    bf16* w1t;    // [32][1024] bf16: W1t[h][k] = a[k]*W1[k][h] (heavy subnets only)
    int F;
};
struct SubP3 { SubP s[3]; };

// ---------------- BatchNorm stats: 32 rows/block, grid (256,3), contention-free ----------
__global__ void __launch_bounds__(256) stats3_kernel(SubP3 P) {
    const SubP p = P.s[blockIdx.z];
    int t = threadIdx.x;
    int blk = blockIdx.x;
    int row0 = blk * 32;
    if (p.F == 1024) {
        f32x4 s = {0.f, 0.f, 0.f, 0.f}, s2 = {0.f, 0.f, 0.f, 0.f};
        const float* xp = p.x + (size_t)row0 * 1024 + t * 4;
        #pragma unroll 8
        for (int r = 0; r < 32; r++) {
            f32x4 v = *(const f32x4*)(xp + (size_t)r * 1024);
            s += v; s2 += v * v;
        }
        int f = t * 4;
        *(f32x4*)&p.sum[(size_t)blk * 2048 + f]   = s;
        *(f32x4*)&p.sumsq[(size_t)blk * 2048 + f] = s2;
    } else {
        __shared__ float ls[16], ls2[16];
        if (t < 16) { ls[t] = 0.f; ls2[t] = 0.f; }
        __syncthreads();
        int F = p.F;
        for (int idx = t; idx < 32 * F; idx += 256) {
            float v = p.x[(size_t)row0 * F + idx];
            int f = idx % 10;            // row0*F = blk*320 ≡ 0 (mod 10)
            atomicAdd(&ls[f], v);        // LDS-scope only
            atomicAdd(&ls2[f], v * v);
        }
        __syncthreads();
        if (t < F) {
            p.sum[(size_t)blk * 2048 + t]   = ls[t];
            p.sumsq[(size_t)blk * 2048 + t] = ls2[t];
        }
    }
}

// ---------------- finalize stats: reduce partials; a[f]; c@W1 -> b1p; W1t bf16 build ----
__global__ void prep3_kernel(SubP3 P) {
    const SubP p = P.s[blockIdx.y];
    int f0 = blockIdx.x * 32;
    if (f0 >= p.F) return;
    int t = threadIdx.x;
    __shared__ float c_sh[32];
    __shared__ float ash[32];
    __shared__ float red[8][33];
    __shared__ float rs[8][33], rs2[8][33];
    int fc = p.F - f0; if (fc > 32) fc = 32;
    int fi = t & 31, g = t >> 5;
    {
        float s = 0.f, s2 = 0.f;
        if (fi < fc) {
            for (int blk = g; blk < SBLK; blk += 8) {
                s  += p.sum[(size_t)blk * 2048 + f0 + fi];
                s2 += p.sumsq[(size_t)blk * 2048 + f0 + fi];
            }
        }
        rs[g][fi] = s; rs2[g][fi] = s2;
    }
    __syncthreads();
    if (t < 32) {
        float c = 0.f, av = 0.f;
        if (t < fc) {
            float sm = 0.f, sq = 0.f;
            #pragma unroll
            for (int gg = 0; gg < 8; gg++) { sm += rs[gg][t]; sq += rs2[gg][t]; }
            int f = f0 + t;
            float mu  = sm * (1.f / 8192.f);
            float var = sq * (1.f / 8192.f) - mu * mu;
            av = p.gamma[f] * rsqrtf(var + 1e-5f);
            p.a[f] = av;
            c = p.beta[f] - mu * av;
        }
        c_sh[t] = c; ash[t] = av;
    }
    __syncthreads();
    int h = t & 31; g = t >> 5;
    float s = 0.f;
    for (int fi2 = g; fi2 < fc; fi2 += 8)
        s += c_sh[fi2] * p.W1[(size_t)(f0 + fi2) * 32 + h];
    red[g][h] = s;
    __syncthreads();
    if (t < 32) {
        float tot = 0.f;
        #pragma unroll
        for (int gg = 0; gg < 8; gg++) tot += red[gg][t];
        atomicAdd(&p.b1p[t], tot);
    }
    // W1t build (heavy subnets): W1t[h][k] = a[k]*W1[k][h], bf16, stride 1024
    if (p.F == 1024) {
        for (int idx = t; idx < 1024; idx += 256) {
            int kk = idx >> 5, hh = idx & 31;
            p.w1t[(size_t)hh * 1024 + f0 + kk] =
                __float2bfloat16(ash[kk] * p.W1[(size_t)(f0 + kk) * 32 + hh]);
        }
    }
}

// ---------------- Subnet MLP: 32 rows/block; heavy layer-1 via bf16 MFMA (R10, verified) ----
__global__ void __launch_bounds__(256) subnet3_kernel(SubP3 P) {
    const SubP p = P.s[blockIdx.y];
    const int F = p.F;
    __shared__ float smem[9760];
    float* Red = smem;            // 3 x 1152
    float* H1  = smem + 3456;     // [32][36]
    float* W23 = smem + 4608;     // [32][33] (pad to 5664)
    float* H2  = smem;            // reuse

    int t = threadIdx.x;
    int row0 = blockIdx.x * 32;
    int kg = t >> 6;
    int lane = t & 63;
    int hg = lane & 7, h0 = hg * 4;
    int rg = (lane >> 3) & 3;
    int ks = lane >> 5;

    if (F == 1024) {
        bf16* Xl = (bf16*)(smem + 5664);   // [32][128] bf16, swizzled (8 KB)
        bf16* Wl = (bf16*)(smem + 7712);   // [32][128] bf16, swizzled (8 KB)
        int xr = t >> 3, xc = (t & 7) * 16;
        int sw = xr & 7;
        int s0 = ((t & 7) * 2) ^ sw, s1 = ((t & 7) * 2 + 1) ^ sw;
        const float* xbase = p.x + (size_t)(row0 + xr) * 1024 + xc;
        const bf16*  wbase = p.w1t + (size_t)xr * 1024 + xc;
        f32x4 xp[4]; s16x8 wp0, wp1;
        #pragma unroll
        for (int i = 0; i < 4; i++) xp[i] = *(const f32x4*)(xbase + i * 4);
        wp0 = *(const s16x8*)(wbase);
        wp1 = *(const s16x8*)(wbase + 8);

        f32x4 acc[2][2] = {};
        int fr = lane & 15, qq = lane >> 4;
        int rsw0 = fr & 7;

        for (int c = 0; c < 8; c++) {
            __builtin_amdgcn_s_barrier();           // prev chunk's LDS reads done
            asm volatile("" ::: "memory");
            {   // pack fp32 -> bf16, swizzled LDS writes
                s16x8 v0, v1;
                #pragma unroll
                for (int i = 0; i < 2; i++)
                    #pragma unroll
                    for (int e = 0; e < 4; e++) {
                        __hip_bfloat16 hb = __float2bfloat16(xp[i][e]);
                        v0[i * 4 + e] = *(short*)&hb;
                    }
                #pragma unroll
                for (int i = 0; i < 2; i++)
                    #pragma unroll
                    for (int e = 0; e < 4; e++) {
                        __hip_bfloat16 hb = __float2bfloat16(xp[2 + i][e]);
                        v1[i * 4 + e] = *(short*)&hb;
                    }
                *(s16x8*)((char*)Xl + xr * 256 + s0 * 16) = v0;
                *(s16x8*)((char*)Xl + xr * 256 + s1 * 16) = v1;
                *(s16x8*)((char*)Wl + xr * 256 + s0 * 16) = wp0;
                *(s16x8*)((char*)Wl + xr * 256 + s1 * 16) = wp1;
            }
            if (c < 7) {
                int k0 = (c + 1) * 128;
                #pragma unroll
                for (int i = 0; i < 4; i++) xp[i] = *(const f32x4*)(xbase + k0 + i * 4);
                wp0 = *(const s16x8*)(wbase + k0);
                wp1 = *(const s16x8*)(wbase + k0 + 8);
            }
            asm volatile("s_waitcnt lgkmcnt(0)" ::: "memory");
            __builtin_amdgcn_sched_barrier(0);
            __builtin_amdgcn_s_barrier();
            asm volatile("" ::: "memory");
            {
                int sx = kg * 4 + qq;
                int sl = (sx ^ rsw0) * 16;
                s16x8 a0 = *(const s16x8*)((char*)Xl + fr * 256 + sl);
                s16x8 a1 = *(const s16x8*)((char*)Xl + (16 + fr) * 256 + sl);
                s16x8 b0 = *(const s16x8*)((char*)Wl + fr * 256 + sl);
                s16x8 b1 = *(const s16x8*)((char*)Wl + (16 + fr) * 256 + sl);
                acc[0][0] = __builtin_amdgcn_mfma_f32_16x16x32_bf16(a0, b0, acc[0][0], 0, 0, 0);
                acc[0][1] = __builtin_amdgcn_mfma_f32_16x16x32_bf16(a0, b1, acc[0][1], 0, 0, 0);
                acc[1][0] = __builtin_amdgcn_mfma_f32_16x16x32_bf16(a1, b0, acc[1][0], 0, 0, 0);
                acc[1][1] = __builtin_amdgcn_mfma_f32_16x16x32_bf16(a1, b1, acc[1][1], 0, 0, 0);
            }
        }
        int col = lane & 15, rowg = (lane >> 4) * 4;
        if (kg > 0) {
            #pragma unroll
            for (int m = 0; m < 2; m++)
                #pragma unroll
                for (int n = 0; n < 2; n++)
                    #pragma unroll
                    for (int r = 0; r < 4; r++)
                        Red[(kg - 1) * 1152 + (m * 16 + rowg + r) * 36 + n * 16 + col] = acc[m][n][r];
        }
        __syncthreads();
        if (kg == 0) {
            #pragma unroll
            for (int m = 0; m < 2; m++)
                #pragma unroll
                for (int n = 0; n < 2; n++) {
                    int cc = n * 16 + col;
                    float bv = p.b1[cc] + p.b1p[cc];
                    #pragma unroll
                    for (int r = 0; r < 4; r++) {
                        int rr = m * 16 + rowg + r;
                        float v = acc[m][n][r] + bv;
                        #pragma unroll
                        for (int pp = 0; pp < 3; pp++)
                            v += Red[pp * 1152 + rr * 36 + cc];
                        H1[rr * 36 + cc] = fmaxf(v, 0.f);
                    }
                }
        }
    } else {
        float* Xt = smem;             // [32][68]
        float* Wt = smem + 2176;      // [64][36]
        float acc[4][8] = {};
        int kbase = (kg * 2 + ks) * 8;
        for (int k0 = 0; k0 < F; k0 += 64) {
            int kc = F - k0; if (kc > 64) kc = 64;
            int kcp = (kc + 3) & ~3;
            __syncthreads();
            for (int idx = t; idx < 32 * kcp; idx += 256) {
                int r = idx / kcp, kk = idx - r * kcp;
                Xt[r * 68 + kk] = (kk < kc) ? p.x[(size_t)(row0 + r) * F + k0 + kk] : 0.f;
            }
            for (int idx = t; idx < kcp * 32; idx += 256) {
                int kk = idx >> 5, hh = idx & 31;
                Wt[kk * 36 + hh] = (kk < kc) ? p.a[k0 + kk] * p.W1[(size_t)(k0 + kk) * 32 + hh] : 0.f;
            }
            __syncthreads();
            #pragma unroll
            for (int s = 0; s < 2; s++) {
                int kk = kbase + s * 4;
                if (kk < kcp) {
                    f32x4 wv[4], xv[8];
                    #pragma unroll
                    for (int j = 0; j < 4; j++)  wv[j]  = *(const f32x4*)&Wt[(kk + j) * 36 + h0];
                    #pragma unroll
                    for (int ri = 0; ri < 8; ri++) xv[ri] = *(const f32x4*)&Xt[(rg + 4 * ri) * 68 + kk];
                    #pragma unroll
                    for (int j = 0; j < 4; j++)
                        #pragma unroll
                        for (int hi = 0; hi < 4; hi++) {
                            float w = wv[j][hi];
                            #pragma unroll
                            for (int ri = 0; ri < 8; ri++)
                                acc[hi][ri] = fmaf(w, xv[ri][j], acc[hi][ri]);
                        }
                }
            }
        }
        #pragma unroll
        for (int hi = 0; hi < 4; hi++)
            #pragma unroll
            for (int ri = 0; ri < 8; ri++)
                acc[hi][ri] += __shfl_xor(acc[hi][ri], 32);
        __syncthreads();
        if (kg > 0 && ks == 0) {
            #pragma unroll
            for (int ri = 0; ri < 8; ri++) {
                int r = rg + 4 * ri;
                f32x4 v = {acc[0][ri], acc[1][ri], acc[2][ri], acc[3][ri]};
                *(f32x4*)&Red[(kg - 1) * 1152 + r * 36 + h0] = v;
            }
        }
        __syncthreads();
        if (kg == 0 && ks == 0) {
            f32x4 b;
            #pragma unroll
            for (int hi = 0; hi < 4; hi++) b[hi] = p.b1[h0 + hi] + p.b1p[h0 + hi];
            #pragma unroll
            for (int ri = 0; ri < 8; ri++) {
                int r = rg + 4 * ri;
                f32x4 v = {acc[0][ri], acc[1][ri], acc[2][ri], acc[3][ri]};
                #pragma unroll
                for (int pp = 0; pp < 3; pp++)
                    v += *(const f32x4*)&Red[pp * 1152 + r * 36 + h0];
                v += b;
                #pragma unroll
                for (int hi = 0; hi < 4; hi++)
                    H1[r * 36 + h0 + hi] = fmaxf(v[hi], 0.f);
            }
        }
    }
    // -------- shared fp32 layers 2/3 (32 rows) --------
    for (int idx = t; idx < 1024; idx += 256) W23[(idx >> 5) * 33 + (idx & 31)] = p.W2[idx];
    __syncthreads();
    int h = t & 31, rq = t >> 5;
    {
        float a2[4] = {};
        for (int q = 0; q < 32; q++) {
            float w = W23[q * 33 + h];
            #pragma unroll
            for (int i = 0; i < 4; i++) a2[i] += H1[(rq * 4 + i) * 36 + q] * w;
        }
        float bv = p.b2[h];
        #pragma unroll
        for (int i = 0; i < 4; i++) H2[(rq * 4 + i) * 36 + h] = fmaxf(a2[i] + bv, 0.f);
    }
    __syncthreads();
    for (int idx = t; idx < 1024; idx += 256) W23[(idx >> 5) * 33 + (idx & 31)] = p.W3[idx];
    __syncthreads();
    {
        float a3[4] = {};
        for (int q = 0; q < 32; q++) {
            float w = W23[q * 33 + h];
            #pragma unroll
            for (int i = 0; i < 4; i++) a3[i] += H2[(rq * 4 + i) * 36 + q] * w;
        }
        float bv = p.b3[h];
        #pragma unroll
        for (int i = 0; i < 4; i++)
            p.hout[(size_t)(row0 + rq * 4 + i) * 32 + h] = fmaxf(a3[i] + bv, 0.f);
    }
}

// ---------------- p1 build (4 rows/block, wave-per-row) + W2t transpose, one launch -------
__global__ void __launch_bounds__(256) build_both(const float* __restrict__ mk_h,
                           const float* __restrict__ us_h,
                           bf16* __restrict__ p1,
                           const float* __restrict__ Wf1, bf16* __restrict__ W2t) {
    int blk = blockIdx.x;
    int t = threadIdx.x;
    if (blk < NB / 4) {
        int r = t >> 6, lane = t & 63;
        int b = blk * 4 + r;
        __shared__ float mk1[4][34], us1[4][34];
        if (lane == 0) { mk1[r][0] = 1.f; us1[r][0] = 1.f; }
        if (lane < 32) mk1[r][lane + 1] = mk_h[(size_t)b * 32 + lane];
        else           us1[r][lane - 31] = us_h[(size_t)b * 32 + (lane - 32)];
        __syncthreads();
        #pragma unroll
        for (int c = 0; c < 3; c++) {
            int chunk = lane + 64 * c;
            if (chunk < 144) {
                int base = chunk * 8;
                s16x8 v;
                #pragma unroll
                for (int e = 0; e < 8; e++) {
                    int idx = base + e;
                    float val = 0.f;
                    if (idx < 1089) {
                        int k = idx / 33, i = idx - k * 33;
                        val = mk1[r][k] * us1[r][i];
                    }
                    __hip_bfloat16 hb = __float2bfloat16(val);
                    v[e] = *(short*)&hb;
                }
                *(s16x8*)(p1 + (size_t)b * KP + base) = v;
            }
        }
    } else {
        int kj = blk - NB / 4;
        int k = kj / 33, j = kj - k * 33;
        __shared__ float tile[1089];
        const float* src = Wf1 + (size_t)k * 35937 + (size_t)j * 1089;
        for (int idx = t; idx < 1089; idx += 256) tile[idx] = src[idx];
        __syncthreads();
        for (int idx = t; idx < 1089; idx += 256) {
            int o = idx / 33, i = idx - o * 33;
            W2t[(size_t)(j * 33 + o) * KP + k * 33 + i] = __float2bfloat16(tile[i * 33 + o]);
        }
        if (k == 0) {
            bf16 z = __float2bfloat16(0.f);
            for (int idx = t; idx < 33 * 63; idx += 256) {
                int o = idx / 63, kkp = 1089 + idx - o * 63;
                W2t[(size_t)(j * 33 + o) * KP + kkp] = z;
            }
        }
    }
}

// ---------------- Main GEMM + fused j-contraction -> hpart[b][nb*33+o] --------------------
// R9 8-phase loop (verified best) unchanged. New epilogue: overlay dead As/Bs LDS with
// hacc[256][33] + cdl[256][33]; each lane LDS-atomic-adds cdl[row][j]*acc into hacc
// (j = gc/33, o = gc%33; gc>=1089 garbage cols skipped -- same cols the old epilogue
// never read); block writes ONE coalesced fp32 partial hpart[(m0+row)*264 + nb*33+o].
// Eliminates S: 18.4MB of scattered 2B stores + 18.9MB re-read -> 8.65MB fp32 each way.
// Numerics: strictly more accurate (drops the S bf16 rounding before contraction).
__global__ void __launch_bounds__(512) gemm_kernel(const bf16* __restrict__ A,   // [NB][KP]
                                                   const bf16* __restrict__ Bt,  // [NP][KP]
                                                   const float* __restrict__ cd_h,
                                                   float* __restrict__ hpart) {  // [NB][264]
    __shared__ __align__(16) char ldsraw[114688];    // As 64KB | Bs 48KB, overlaid later
    bf16* As0 = (bf16*)ldsraw;                       // [2][256*64]
    bf16* Bs0 = (bf16*)(ldsraw + 65536);             // [2][192*64]
    int t = threadIdx.x;
    int wv = t >> 6, lane = t & 63;
    int m0 = blockIdx.x * 256;
    int n0 = blockIdx.y * 144;
    int fr = lane & 15;
    int q  = lane >> 4;
    int lr8 = lane >> 3;
    int sslot = (lane & 7) ^ lr8;

    const bf16* Ag = A  + (size_t)(m0 + wv * 32 + lr8) * KP + sslot * 8;
    const bf16* Bg = Bt + (size_t)(n0 + wv * 24 + lr8) * KP + sslot * 8;

    f32x4 acc[2][9] = {};

    auto stageA = [&](int buf, int T) {
        bf16* Ad = As0 + buf * 16384 + wv * 32 * 64;
        const bf16* s = Ag + T * 64;
        #pragma unroll
        for (int i = 0; i < 4; i++)
            __builtin_amdgcn_global_load_lds(
                (const __attribute__((address_space(1))) void*)(s + (size_t)i * 8 * KP),
                (__attribute__((address_space(3))) void*)(Ad + i * 512), 16, 0, 0);
    };
    auto stageB = [&](int buf, int T) {
        bf16* Bd = Bs0 + buf * 12288 + wv * 24 * 64;
        const bf16* s = Bg + T * 64;
        #pragma unroll
        for (int c = 0; c < 3; c++)
            __builtin_amdgcn_global_load_lds(
                (const __attribute__((address_space(1))) void*)(s + (size_t)c * 8 * KP),
                (__attribute__((address_space(3))) void*)(Bd + c * 512), 16, 0, 0);
    };

    stageA(0, 0);
    stageB(0, 0);

    for (int T = 0; T < NKT; T++) {
        int b = T & 1;
        const bf16* Ab = As0 + b * 16384;
        const bf16* Bb = Bs0 + b * 12288;
        if (T < NKT - 1) {
            stageA(b ^ 1, T + 1);
            asm volatile("s_waitcnt vmcnt(4)" ::: "memory");
        } else {
            asm volatile("s_waitcnt vmcnt(0)" ::: "memory");
        }
        __builtin_amdgcn_s_barrier();
        asm volatile("" ::: "memory");
        {
            int sl = (q ^ (fr & 7)) * 8;
            s16x8 af0 = *(const s16x8*)(Ab + (wv * 32 + fr) * 64 + sl);
            s16x8 af1 = *(const s16x8*)(Ab + (wv * 32 + 16 + fr) * 64 + sl);
            s16x8 bfv[9];
            #pragma unroll
            for (int n2 = 0; n2 < 9; n2++)
                bfv[n2] = *(const s16x8*)(Bb + (n2 * 16 + fr) * 64 + sl);
            __builtin_amdgcn_s_setprio(1);
            #pragma unroll
            for (int n2 = 0; n2 < 9; n2++) {
                acc[0][n2] = __builtin_amdgcn_mfma_f32_16x16x32_bf16(af0, bfv[n2], acc[0][n2], 0, 0, 0);
                acc[1][n2] = __builtin_amdgcn_mfma_f32_16x16x32_bf16(af1, bfv[n2], acc[1][n2], 0, 0, 0);
            }
            __builtin_amdgcn_s_setprio(0);
        }
        if (T < NKT - 1) stageB(b ^ 1, T + 1);
        {
            int sl = ((4 + q) ^ (fr & 7)) * 8;
            s16x8 af0 = *(const s16x8*)(Ab + (wv * 32 + fr) * 64 + sl);
            s16x8 af1 = *(const s16x8*)(Ab + (wv * 32 + 16 + fr) * 64 + sl);
            s16x8 bfv[9];
            #pragma unroll
            for (int n2 = 0; n2 < 9; n2++)
                bfv[n2] = *(const s16x8*)(Bb + (n2 * 16 + fr) * 64 + sl);
            __builtin_amdgcn_s_setprio(1);
            #pragma unroll
            for (int n2 = 0; n2 < 9; n2++) {
                acc[0][n2] = __builtin_amdgcn_mfma_f32_16x16x32_bf16(af0, bfv[n2], acc[0][n2], 0, 0, 0);
                acc[1][n2] = __builtin_amdgcn_mfma_f32_16x16x32_bf16(af1, bfv[n2], acc[1][n2], 0, 0, 0);
            }
            __builtin_amdgcn_s_setprio(0);
        }
        asm volatile("s_waitcnt lgkmcnt(0)" ::: "memory");
        __builtin_amdgcn_sched_barrier(0);
        __builtin_amdgcn_s_barrier();
        asm volatile("" ::: "memory");
    }

    // ---- fused j-contraction (LDS overlay; As/Bs dead after final barrier) ----
    float* hacc = (float*)ldsraw;            // [256][33] = 33792 B
    float* cdl  = (float*)(ldsraw + 33792);  // [256][33]
    for (int idx = t; idx < 8448; idx += 512) hacc[idx] = 0.f;
    for (int idx = t; idx < 8448; idx += 512) {
        int row = idx / 33, j = idx - row * 33;
        cdl[idx] = (j == 0) ? 1.f : cd_h[(size_t)(m0 + row) * 32 + (j - 1)];
    }
    __syncthreads();
    {
        int col = lane & 15, rowg4 = (lane >> 4) * 4;
        #pragma unroll
        for (int n2 = 0; n2 < 9; n2++) {
            int gc = n0 + n2 * 16 + col;
            if (gc < 1089) {
                int j = gc / 33;
                int o = gc - j * 33;
                #pragma unroll
                for (int mt = 0; mt < 2; mt++)
                    #pragma unroll
                    for (int r = 0; r < 4; r++) {
                        int lrow = wv * 32 + mt * 16 + rowg4 + r;
                        atomicAdd(&hacc[lrow * 33 + o], cdl[lrow * 33 + j] * acc[mt][n2][r]);
                    }
            }
        }
    }
    __syncthreads();
    for (int idx = t; idx < 8448; idx += 512) {
        int row = idx / 33, o = idx - row * 33;
        hpart[(size_t)(m0 + row) * 264 + blockIdx.y * 33 + o] = hacc[idx];
    }
}

// ---------------- Reduce: h = relu(bf1 + sum_nb hpart), then 33x5 + sigmoid ----------------
__global__ void __launch_bounds__(256) reduce_out(const float* __restrict__ hpart,
                                const float* __restrict__ bf1, const float* __restrict__ Wf2,
                                const float* __restrict__ bf2, float* __restrict__ out) {
    int w = threadIdx.x >> 6;
    int lane = threadIdx.x & 63;
    int b = blockIdx.x * 4 + w;
    __shared__ float hsh[4][40];
    if (lane < 33) {
        const float* hp = hpart + (size_t)b * 264 + lane;
        float a = bf1[lane];
        #pragma unroll
        for (int nb = 0; nb < 8; nb++) a += hp[nb * 33];
        hsh[w][lane] = fmaxf(a, 0.f);
    }
    __syncthreads();
    if (lane < 5) {
        float o = bf2[lane];
        for (int q = 0; q < 33; q++) o += hsh[w][q] * Wf2[q * 5 + lane];
        out[(size_t)b * 5 + lane] = 1.f / (1.f + expf(-o));
    }
}

extern "C" void kernel_launch(void* const* d_in, const int* in_sizes, int n_in,
                              void* d_out, int out_size, void* d_ws, size_t ws_size,
                              hipStream_t stream) {
    const float* US_x     = (const float*)d_in[0];
    const float* CDFI_x   = (const float*)d_in[1];
    const float* marker_x = (const float*)d_in[2];
    const float* Wf1      = (const float*)d_in[27];
    const float* bf1      = (const float*)d_in[28];
    const float* Wf2      = (const float*)d_in[29];
    const float* bf2      = (const float*)d_in[30];
    float* out = (float*)d_out;

    char* ws = (char*)d_ws;
    size_t off = 0;
    auto alloc = [&](size_t bytes) -> void* {
        void* p = ws + off;
        off = (off + bytes + 255) & ~(size_t)255;
        return p;
    };

    float* b1p_buf  = (float*)alloc(3 * 128 * sizeof(float));                 // zeroed
    float* pstat    = (float*)alloc((size_t)3 * SBLK * 2048 * sizeof(float)); // partials
    bf16*  w1t_buf  = (bf16*)alloc((size_t)3 * 32 * 1024 * 2);                // W1t per subnet
    float* a_buf[3], *h_buf[3];
    for (int i = 0; i < 3; i++) {
        a_buf[i] = (float*)alloc(1024 * 4);
        h_buf[i] = (float*)alloc((size_t)NB * 32 * 4);
    }
    bf16*  p1   = (bf16*)alloc((size_t)NB * KP * 2);
    bf16*  W2t  = (bf16*)alloc((size_t)NP * KP * 2);
    float* hpart = (float*)alloc((size_t)NB * 264 * 4);  // also absorbs B-pad OOB reads

    SubP3 P;
    const float* xs[3] = {US_x, CDFI_x, marker_x};
    int Fs[3] = {1024, 1024, 10};
    for (int i = 0; i < 3; i++) {
        int base = 3 + i * 8;
        P.s[i].x     = xs[i];
        P.s[i].gamma = (const float*)d_in[base + 0];
        P.s[i].beta  = (const float*)d_in[base + 1];
        P.s[i].W1    = (const float*)d_in[base + 2];
        P.s[i].b1    = (const float*)d_in[base + 3];
        P.s[i].W2    = (const float*)d_in[base + 4];
        P.s[i].b2    = (const float*)d_in[base + 5];
        P.s[i].W3    = (const float*)d_in[base + 6];
        P.s[i].b3    = (const float*)d_in[base + 7];
        P.s[i].sum   = pstat + (size_t)i * SBLK * 2048;
        P.s[i].sumsq = pstat + (size_t)i * SBLK * 2048 + 1024;
        P.s[i].b1p   = b1p_buf + i * 128;
        P.s[i].a     = a_buf[i];
        P.s[i].hout  = h_buf[i];
        P.s[i].w1t   = w1t_buf + (size_t)i * 32 * 1024;
        P.s[i].F     = Fs[i];
    }

    float* us_h = h_buf[0];
    float* cd_h = h_buf[1];
    float* mk_h = h_buf[2];

    hipMemsetAsync(b1p_buf, 0, 3 * 128 * sizeof(float), stream);

    stats3_kernel<<<dim3(SBLK, 1, 3), 256, 0, stream>>>(P);
    prep3_kernel<<<dim3(32, 3), 256, 0, stream>>>(P);
    subnet3_kernel<<<dim3(256, 3), 256, 0, stream>>>(P);

    build_both<<<NB / 4 + 1089, 256, 0, stream>>>(mk_h, us_h, p1, Wf1, W2t);

    gemm_kernel<<<dim3(NB / 256, NP / 144), 512, 0, stream>>>(p1, W2t, cd_h, hpart);

    reduce_out<<<NB / 4, 256, 0, stream>>>(hpart, bf1, Wf2, bf2, out);
}

// Round 12
// 233.742 us; speedup vs baseline: 1.1453x; 1.1453x over previous
//
#include <hip/hip_runtime.h>
#include <hip/hip_bf16.h>
#include <math.h>

typedef __hip_bfloat16 bf16;
typedef __attribute__((ext_vector_type(4))) float f32x4;
typedef __attribute__((ext_vector_type(8))) short s16x8;

#define NB 8192
#define KP 1152   // padded K: 1089 -> 18*64
#define NP 1152   // padded N: 1089 -> 8*144
#define NKT 18    // K-tiles of 64
#define SBLK 256  // stats blocks per subnet (32 rows each)

struct SubP {
    const float* x; const float* gamma; const float* beta;
    const float* W1; const float* b1; const float* W2; const float* b2;
    const float* W3; const float* b3;
    float* sum; float* sumsq; float* a; float* b1p; float* hout;
    bf16* w1t;    // [32][1024] bf16: W1t[h][k] = a[k]*W1[k][h] (heavy subnets only)
    int F;
};
struct SubP3 { SubP s[3]; };

// ---------------- BatchNorm stats: 32 rows/block, grid (256,3), contention-free ----------
__global__ void __launch_bounds__(256) stats3_kernel(SubP3 P) {
    const SubP p = P.s[blockIdx.z];
    int t = threadIdx.x;
    int blk = blockIdx.x;
    int row0 = blk * 32;
    if (p.F == 1024) {
        f32x4 s = {0.f, 0.f, 0.f, 0.f}, s2 = {0.f, 0.f, 0.f, 0.f};
        const float* xp = p.x + (size_t)row0 * 1024 + t * 4;
        #pragma unroll 8
        for (int r = 0; r < 32; r++) {
            f32x4 v = *(const f32x4*)(xp + (size_t)r * 1024);
            s += v; s2 += v * v;
        }
        int f = t * 4;
        *(f32x4*)&p.sum[(size_t)blk * 2048 + f]   = s;
        *(f32x4*)&p.sumsq[(size_t)blk * 2048 + f] = s2;
    } else {
        __shared__ float ls[16], ls2[16];
        if (t < 16) { ls[t] = 0.f; ls2[t] = 0.f; }
        __syncthreads();
        int F = p.F;
        for (int idx = t; idx < 32 * F; idx += 256) {
            float v = p.x[(size_t)row0 * F + idx];
            int f = idx % 10;            // row0*F = blk*320 ≡ 0 (mod 10)
            atomicAdd(&ls[f], v);        // LDS-scope only
            atomicAdd(&ls2[f], v * v);
        }
        __syncthreads();
        if (t < F) {
            p.sum[(size_t)blk * 2048 + t]   = ls[t];
            p.sumsq[(size_t)blk * 2048 + t] = ls2[t];
        }
    }
}

// ---------------- finalize stats: reduce partials; a[f]; c@W1 -> b1p; W1t bf16 build ----
__global__ void prep3_kernel(SubP3 P) {
    const SubP p = P.s[blockIdx.y];
    int f0 = blockIdx.x * 32;
    if (f0 >= p.F) return;
    int t = threadIdx.x;
    __shared__ float c_sh[32];
    __shared__ float ash[32];
    __shared__ float red[8][33];
    __shared__ float rs[8][33], rs2[8][33];
    int fc = p.F - f0; if (fc > 32) fc = 32;
    int fi = t & 31, g = t >> 5;
    {
        float s = 0.f, s2 = 0.f;
        if (fi < fc) {
            for (int blk = g; blk < SBLK; blk += 8) {
                s  += p.sum[(size_t)blk * 2048 + f0 + fi];
                s2 += p.sumsq[(size_t)blk * 2048 + f0 + fi];
            }
        }
        rs[g][fi] = s; rs2[g][fi] = s2;
    }
    __syncthreads();
    if (t < 32) {
        float c = 0.f, av = 0.f;
        if (t < fc) {
            float sm = 0.f, sq = 0.f;
            #pragma unroll
            for (int gg = 0; gg < 8; gg++) { sm += rs[gg][t]; sq += rs2[gg][t]; }
            int f = f0 + t;
            float mu  = sm * (1.f / 8192.f);
            float var = sq * (1.f / 8192.f) - mu * mu;
            av = p.gamma[f] * rsqrtf(var + 1e-5f);
            p.a[f] = av;
            c = p.beta[f] - mu * av;
        }
        c_sh[t] = c; ash[t] = av;
    }
    __syncthreads();
    int h = t & 31; g = t >> 5;
    float s = 0.f;
    for (int fi2 = g; fi2 < fc; fi2 += 8)
        s += c_sh[fi2] * p.W1[(size_t)(f0 + fi2) * 32 + h];
    red[g][h] = s;
    __syncthreads();
    if (t < 32) {
        float tot = 0.f;
        #pragma unroll
        for (int gg = 0; gg < 8; gg++) tot += red[gg][t];
        atomicAdd(&p.b1p[t], tot);
    }
    // W1t build (heavy subnets): W1t[h][k] = a[k]*W1[k][h], bf16, stride 1024
    if (p.F == 1024) {
        for (int idx = t; idx < 1024; idx += 256) {
            int kk = idx >> 5, hh = idx & 31;
            p.w1t[(size_t)hh * 1024 + f0 + kk] =
                __float2bfloat16(ash[kk] * p.W1[(size_t)(f0 + kk) * 32 + hh]);
        }
    }
}

// ---------------- Subnet MLP: 32 rows/block; heavy layer-1 via bf16 MFMA (R10, verified) ----
__global__ void __launch_bounds__(256) subnet3_kernel(SubP3 P) {
    const SubP p = P.s[blockIdx.y];
    const int F = p.F;
    __shared__ float smem[9760];
    float* Red = smem;            // 3 x 1152
    float* H1  = smem + 3456;     // [32][36]
    float* W23 = smem + 4608;     // [32][33] (pad to 5664)
    float* H2  = smem;            // reuse

    int t = threadIdx.x;
    int row0 = blockIdx.x * 32;
    int kg = t >> 6;
    int lane = t & 63;
    int hg = lane & 7, h0 = hg * 4;
    int rg = (lane >> 3) & 3;
    int ks = lane >> 5;

    if (F == 1024) {
        bf16* Xl = (bf16*)(smem + 5664);   // [32][128] bf16, swizzled (8 KB)
        bf16* Wl = (bf16*)(smem + 7712);   // [32][128] bf16, swizzled (8 KB)
        int xr = t >> 3, xc = (t & 7) * 16;
        int sw = xr & 7;
        int s0 = ((t & 7) * 2) ^ sw, s1 = ((t & 7) * 2 + 1) ^ sw;
        const float* xbase = p.x + (size_t)(row0 + xr) * 1024 + xc;
        const bf16*  wbase = p.w1t + (size_t)xr * 1024 + xc;
        f32x4 xp[4]; s16x8 wp0, wp1;
        #pragma unroll
        for (int i = 0; i < 4; i++) xp[i] = *(const f32x4*)(xbase + i * 4);
        wp0 = *(const s16x8*)(wbase);
        wp1 = *(const s16x8*)(wbase + 8);

        f32x4 acc[2][2] = {};
        int fr = lane & 15, qq = lane >> 4;
        int rsw0 = fr & 7;

        for (int c = 0; c < 8; c++) {
            __builtin_amdgcn_s_barrier();           // prev chunk's LDS reads done
            asm volatile("" ::: "memory");
            {   // pack fp32 -> bf16, swizzled LDS writes
                s16x8 v0, v1;
                #pragma unroll
                for (int i = 0; i < 2; i++)
                    #pragma unroll
                    for (int e = 0; e < 4; e++) {
                        __hip_bfloat16 hb = __float2bfloat16(xp[i][e]);
                        v0[i * 4 + e] = *(short*)&hb;
                    }
                #pragma unroll
                for (int i = 0; i < 2; i++)
                    #pragma unroll
                    for (int e = 0; e < 4; e++) {
                        __hip_bfloat16 hb = __float2bfloat16(xp[2 + i][e]);
                        v1[i * 4 + e] = *(short*)&hb;
                    }
                *(s16x8*)((char*)Xl + xr * 256 + s0 * 16) = v0;
                *(s16x8*)((char*)Xl + xr * 256 + s1 * 16) = v1;
                *(s16x8*)((char*)Wl + xr * 256 + s0 * 16) = wp0;
                *(s16x8*)((char*)Wl + xr * 256 + s1 * 16) = wp1;
            }
            if (c < 7) {
                int k0 = (c + 1) * 128;
                #pragma unroll
                for (int i = 0; i < 4; i++) xp[i] = *(const f32x4*)(xbase + k0 + i * 4);
                wp0 = *(const s16x8*)(wbase + k0);
                wp1 = *(const s16x8*)(wbase + k0 + 8);
            }
            asm volatile("s_waitcnt lgkmcnt(0)" ::: "memory");
            __builtin_amdgcn_sched_barrier(0);
            __builtin_amdgcn_s_barrier();
            asm volatile("" ::: "memory");
            {
                int sx = kg * 4 + qq;
                int sl = (sx ^ rsw0) * 16;
                s16x8 a0 = *(const s16x8*)((char*)Xl + fr * 256 + sl);
                s16x8 a1 = *(const s16x8*)((char*)Xl + (16 + fr) * 256 + sl);
                s16x8 b0 = *(const s16x8*)((char*)Wl + fr * 256 + sl);
                s16x8 b1 = *(const s16x8*)((char*)Wl + (16 + fr) * 256 + sl);
                acc[0][0] = __builtin_amdgcn_mfma_f32_16x16x32_bf16(a0, b0, acc[0][0], 0, 0, 0);
                acc[0][1] = __builtin_amdgcn_mfma_f32_16x16x32_bf16(a0, b1, acc[0][1], 0, 0, 0);
                acc[1][0] = __builtin_amdgcn_mfma_f32_16x16x32_bf16(a1, b0, acc[1][0], 0, 0, 0);
                acc[1][1] = __builtin_amdgcn_mfma_f32_16x16x32_bf16(a1, b1, acc[1][1], 0, 0, 0);
            }
        }
        int col = lane & 15, rowg = (lane >> 4) * 4;
        if (kg > 0) {
            #pragma unroll
            for (int m = 0; m < 2; m++)
                #pragma unroll
                for (int n = 0; n < 2; n++)
                    #pragma unroll
                    for (int r = 0; r < 4; r++)
                        Red[(kg - 1) * 1152 + (m * 16 + rowg + r) * 36 + n * 16 + col] = acc[m][n][r];
        }
        __syncthreads();
        if (kg == 0) {
            #pragma unroll
            for (int m = 0; m < 2; m++)
                #pragma unroll
                for (int n = 0; n < 2; n++) {
                    int cc = n * 16 + col;
                    float bv = p.b1[cc] + p.b1p[cc];
                    #pragma unroll
                    for (int r = 0; r < 4; r++) {
                        int rr = m * 16 + rowg + r;
                        float v = acc[m][n][r] + bv;
                        #pragma unroll
                        for (int pp = 0; pp < 3; pp++)
                            v += Red[pp * 1152 + rr * 36 + cc];
                        H1[rr * 36 + cc] = fmaxf(v, 0.f);
                    }
                }
        }
    } else {
        float* Xt = smem;             // [32][68]
        float* Wt = smem + 2176;      // [64][36]
        float acc[4][8] = {};
        int kbase = (kg * 2 + ks) * 8;
        for (int k0 = 0; k0 < F; k0 += 64) {
            int kc = F - k0; if (kc > 64) kc = 64;
            int kcp = (kc + 3) & ~3;
            __syncthreads();
            for (int idx = t; idx < 32 * kcp; idx += 256) {
                int r = idx / kcp, kk = idx - r * kcp;
                Xt[r * 68 + kk] = (kk < kc) ? p.x[(size_t)(row0 + r) * F + k0 + kk] : 0.f;
            }
            for (int idx = t; idx < kcp * 32; idx += 256) {
                int kk = idx >> 5, hh = idx & 31;
                Wt[kk * 36 + hh] = (kk < kc) ? p.a[k0 + kk] * p.W1[(size_t)(k0 + kk) * 32 + hh] : 0.f;
            }
            __syncthreads();
            #pragma unroll
            for (int s = 0; s < 2; s++) {
                int kk = kbase + s * 4;
                if (kk < kcp) {
                    f32x4 wv[4], xv[8];
                    #pragma unroll
                    for (int j = 0; j < 4; j++)  wv[j]  = *(const f32x4*)&Wt[(kk + j) * 36 + h0];
                    #pragma unroll
                    for (int ri = 0; ri < 8; ri++) xv[ri] = *(const f32x4*)&Xt[(rg + 4 * ri) * 68 + kk];
                    #pragma unroll
                    for (int j = 0; j < 4; j++)
                        #pragma unroll
                        for (int hi = 0; hi < 4; hi++) {
                            float w = wv[j][hi];
                            #pragma unroll
                            for (int ri = 0; ri < 8; ri++)
                                acc[hi][ri] = fmaf(w, xv[ri][j], acc[hi][ri]);
                        }
                }
            }
        }
        #pragma unroll
        for (int hi = 0; hi < 4; hi++)
            #pragma unroll
            for (int ri = 0; ri < 8; ri++)
                acc[hi][ri] += __shfl_xor(acc[hi][ri], 32);
        __syncthreads();
        if (kg > 0 && ks == 0) {
            #pragma unroll
            for (int ri = 0; ri < 8; ri++) {
                int r = rg + 4 * ri;
                f32x4 v = {acc[0][ri], acc[1][ri], acc[2][ri], acc[3][ri]};
                *(f32x4*)&Red[(kg - 1) * 1152 + r * 36 + h0] = v;
            }
        }
        __syncthreads();
        if (kg == 0 && ks == 0) {
            f32x4 b;
            #pragma unroll
            for (int hi = 0; hi < 4; hi++) b[hi] = p.b1[h0 + hi] + p.b1p[h0 + hi];
            #pragma unroll
            for (int ri = 0; ri < 8; ri++) {
                int r = rg + 4 * ri;
                f32x4 v = {acc[0][ri], acc[1][ri], acc[2][ri], acc[3][ri]};
                #pragma unroll
                for (int pp = 0; pp < 3; pp++)
                    v += *(const f32x4*)&Red[pp * 1152 + r * 36 + h0];
                v += b;
                #pragma unroll
                for (int hi = 0; hi < 4; hi++)
                    H1[r * 36 + h0 + hi] = fmaxf(v[hi], 0.f);
            }
        }
    }
    // -------- shared fp32 layers 2/3 (32 rows) --------
    for (int idx = t; idx < 1024; idx += 256) W23[(idx >> 5) * 33 + (idx & 31)] = p.W2[idx];
    __syncthreads();
    int h = t & 31, rq = t >> 5;
    {
        float a2[4] = {};
        for (int q = 0; q < 32; q++) {
            float w = W23[q * 33 + h];
            #pragma unroll
            for (int i = 0; i < 4; i++) a2[i] += H1[(rq * 4 + i) * 36 + q] * w;
        }
        float bv = p.b2[h];
        #pragma unroll
        for (int i = 0; i < 4; i++) H2[(rq * 4 + i) * 36 + h] = fmaxf(a2[i] + bv, 0.f);
    }
    __syncthreads();
    for (int idx = t; idx < 1024; idx += 256) W23[(idx >> 5) * 33 + (idx & 31)] = p.W3[idx];
    __syncthreads();
    {
        float a3[4] = {};
        for (int q = 0; q < 32; q++) {
            float w = W23[q * 33 + h];
            #pragma unroll
            for (int i = 0; i < 4; i++) a3[i] += H2[(rq * 4 + i) * 36 + q] * w;
        }
        float bv = p.b3[h];
        #pragma unroll
        for (int i = 0; i < 4; i++)
            p.hout[(size_t)(row0 + rq * 4 + i) * 32 + h] = fmaxf(a3[i] + bv, 0.f);
    }
}

// ---------------- p1 build (4 rows/block, wave-per-row) + W2t transpose, one launch -------
__global__ void __launch_bounds__(256) build_both(const float* __restrict__ mk_h,
                           const float* __restrict__ us_h,
                           bf16* __restrict__ p1,
                           const float* __restrict__ Wf1, bf16* __restrict__ W2t) {
    int blk = blockIdx.x;
    int t = threadIdx.x;
    if (blk < NB / 4) {
        int r = t >> 6, lane = t & 63;
        int b = blk * 4 + r;
        __shared__ float mk1[4][34], us1[4][34];
        if (lane == 0) { mk1[r][0] = 1.f; us1[r][0] = 1.f; }
        if (lane < 32) mk1[r][lane + 1] = mk_h[(size_t)b * 32 + lane];
        else           us1[r][lane - 31] = us_h[(size_t)b * 32 + (lane - 32)];
        __syncthreads();
        #pragma unroll
        for (int c = 0; c < 3; c++) {
            int chunk = lane + 64 * c;
            if (chunk < 144) {
                int base = chunk * 8;
                s16x8 v;
                #pragma unroll
                for (int e = 0; e < 8; e++) {
                    int idx = base + e;
                    float val = 0.f;
                    if (idx < 1089) {
                        int k = idx / 33, i = idx - k * 33;
                        val = mk1[r][k] * us1[r][i];
                    }
                    __hip_bfloat16 hb = __float2bfloat16(val);
                    v[e] = *(short*)&hb;
                }
                *(s16x8*)(p1 + (size_t)b * KP + base) = v;
            }
        }
    } else {
        int kj = blk - NB / 4;
        int k = kj / 33, j = kj - k * 33;
        __shared__ float tile[1089];
        const float* src = Wf1 + (size_t)k * 35937 + (size_t)j * 1089;
        for (int idx = t; idx < 1089; idx += 256) tile[idx] = src[idx];
        __syncthreads();
        for (int idx = t; idx < 1089; idx += 256) {
            int o = idx / 33, i = idx - o * 33;
            W2t[(size_t)(j * 33 + o) * KP + k * 33 + i] = __float2bfloat16(tile[i * 33 + o]);
        }
        if (k == 0) {
            bf16 z = __float2bfloat16(0.f);
            for (int idx = t; idx < 33 * 63; idx += 256) {
                int o = idx / 63, kkp = 1089 + idx - o * 63;
                W2t[(size_t)(j * 33 + o) * KP + kkp] = z;
            }
        }
    }
}

// ---------------- Main GEMM: R9 8-phase-family (verified best) -- FROZEN ----------------
__global__ void __launch_bounds__(512) gemm_kernel(const bf16* __restrict__ A,   // [NB][KP]
                                                   const bf16* __restrict__ Bt,  // [NP][KP]
                                                   bf16* __restrict__ S) {       // [NB][NP]
    __shared__ __align__(16) bf16 As[2][256 * 64];   // 64 KB
    __shared__ __align__(16) bf16 Bs[2][192 * 64];   // 48 KB (rows 144..191 = pad)
    int t = threadIdx.x;
    int wv = t >> 6, lane = t & 63;
    int m0 = blockIdx.x * 256;
    int n0 = blockIdx.y * 144;
    int fr = lane & 15;
    int q  = lane >> 4;
    int lr8 = lane >> 3;
    int sslot = (lane & 7) ^ lr8;

    const bf16* Ag = A  + (size_t)(m0 + wv * 32 + lr8) * KP + sslot * 8;
    const bf16* Bg = Bt + (size_t)(n0 + wv * 24 + lr8) * KP + sslot * 8;

    f32x4 acc[2][9] = {};

    auto stageA = [&](int buf, int T) {
        bf16* Ad = &As[buf][wv * 32 * 64];
        const bf16* s = Ag + T * 64;
        #pragma unroll
        for (int i = 0; i < 4; i++)
            __builtin_amdgcn_global_load_lds(
                (const __attribute__((address_space(1))) void*)(s + (size_t)i * 8 * KP),
                (__attribute__((address_space(3))) void*)(Ad + i * 512), 16, 0, 0);
    };
    auto stageB = [&](int buf, int T) {
        bf16* Bd = &Bs[buf][wv * 24 * 64];
        const bf16* s = Bg + T * 64;
        #pragma unroll
        for (int c = 0; c < 3; c++)
            __builtin_amdgcn_global_load_lds(
                (const __attribute__((address_space(1))) void*)(s + (size_t)c * 8 * KP),
                (__attribute__((address_space(3))) void*)(Bd + c * 512), 16, 0, 0);
    };

    stageA(0, 0);
    stageB(0, 0);

    for (int T = 0; T < NKT; T++) {
        int b = T & 1;
        const bf16* Ab = &As[b][0];
        const bf16* Bb = &Bs[b][0];
        if (T < NKT - 1) {
            stageA(b ^ 1, T + 1);
            asm volatile("s_waitcnt vmcnt(4)" ::: "memory");
        } else {
            asm volatile("s_waitcnt vmcnt(0)" ::: "memory");
        }
        __builtin_amdgcn_s_barrier();
        asm volatile("" ::: "memory");
        {
            int sl = (q ^ (fr & 7)) * 8;
            s16x8 af0 = *(const s16x8*)(Ab + (wv * 32 + fr) * 64 + sl);
            s16x8 af1 = *(const s16x8*)(Ab + (wv * 32 + 16 + fr) * 64 + sl);
            s16x8 bfv[9];
            #pragma unroll
            for (int n2 = 0; n2 < 9; n2++)
                bfv[n2] = *(const s16x8*)(Bb + (n2 * 16 + fr) * 64 + sl);
            __builtin_amdgcn_s_setprio(1);
            #pragma unroll
            for (int n2 = 0; n2 < 9; n2++) {
                acc[0][n2] = __builtin_amdgcn_mfma_f32_16x16x32_bf16(af0, bfv[n2], acc[0][n2], 0, 0, 0);
                acc[1][n2] = __builtin_amdgcn_mfma_f32_16x16x32_bf16(af1, bfv[n2], acc[1][n2], 0, 0, 0);
            }
            __builtin_amdgcn_s_setprio(0);
        }
        if (T < NKT - 1) stageB(b ^ 1, T + 1);
        {
            int sl = ((4 + q) ^ (fr & 7)) * 8;
            s16x8 af0 = *(const s16x8*)(Ab + (wv * 32 + fr) * 64 + sl);
            s16x8 af1 = *(const s16x8*)(Ab + (wv * 32 + 16 + fr) * 64 + sl);
            s16x8 bfv[9];
            #pragma unroll
            for (int n2 = 0; n2 < 9; n2++)
                bfv[n2] = *(const s16x8*)(Bb + (n2 * 16 + fr) * 64 + sl);
            __builtin_amdgcn_s_setprio(1);
            #pragma unroll
            for (int n2 = 0; n2 < 9; n2++) {
                acc[0][n2] = __builtin_amdgcn_mfma_f32_16x16x32_bf16(af0, bfv[n2], acc[0][n2], 0, 0, 0);
                acc[1][n2] = __builtin_amdgcn_mfma_f32_16x16x32_bf16(af1, bfv[n2], acc[1][n2], 0, 0, 0);
            }
            __builtin_amdgcn_s_setprio(0);
        }
        asm volatile("s_waitcnt lgkmcnt(0)" ::: "memory");
        __builtin_amdgcn_sched_barrier(0);
        __builtin_amdgcn_s_barrier();
        asm volatile("" ::: "memory");
    }

    int col = lane & 15, rowg = (lane >> 4) * 4;
    #pragma unroll
    for (int mt = 0; mt < 2; mt++)
        #pragma unroll
        for (int n2 = 0; n2 < 9; n2++)
            #pragma unroll
            for (int r = 0; r < 4; r++) {
                int gr = m0 + wv * 32 + mt * 16 + rowg + r;
                int gc = n0 + n2 * 16 + col;
                S[(size_t)gr * NP + gc] = __float2bfloat16(acc[mt][n2][r]);
            }
}

// ---------------- Epilogue: stage S rows as bf16 in LDS, contract j, 33x5 + sigmoid ----------
__global__ void __launch_bounds__(256) epilogue_kernel(const bf16* __restrict__ S,
                                const float* __restrict__ cd_h,
                                const float* __restrict__ bf1, const float* __restrict__ Wf2,
                                const float* __restrict__ bf2, float* __restrict__ out) {
    int w = threadIdx.x >> 6;
    int lane = threadIdx.x & 63;
    int b = blockIdx.x * 4 + w;
    __shared__ __align__(16) unsigned short Sl[4][1152];
    __shared__ float cdsh[4][33];
    __shared__ float hsh[4][40];
    const bf16* Srow = S + (size_t)b * NP;
    #pragma unroll
    for (int pass = 0; pass < 3; pass++) {
        int idx = lane + pass * 64;
        if (idx < 144)
            *(s16x8*)&Sl[w][idx * 8] = *(const s16x8*)(Srow + idx * 8);
    }
    if (lane == 0) cdsh[w][0] = 1.f;
    if (lane < 32) cdsh[w][lane + 1] = cd_h[(size_t)b * 32 + lane];
    __syncthreads();
    if (lane < 33) {
        float acc = bf1[lane];
        #pragma unroll 3
        for (int j = 0; j < 33; j++) {
            unsigned short sv = Sl[w][j * 33 + lane];
            acc += cdsh[w][j] * __bfloat162float(*(bf16*)&sv);
        }
        hsh[w][lane] = fmaxf(acc, 0.f);
    }
    __syncthreads();
    if (lane < 5) {
        float o = bf2[lane];
        for (int q = 0; q < 33; q++) o += hsh[w][q] * Wf2[q * 5 + lane];
        out[(size_t)b * 5 + lane] = 1.f / (1.f + expf(-o));
    }
}

extern "C" void kernel_launch(void* const* d_in, const int* in_sizes, int n_in,
                              void* d_out, int out_size, void* d_ws, size_t ws_size,
                              hipStream_t stream) {
    const float* US_x     = (const float*)d_in[0];
    const float* CDFI_x   = (const float*)d_in[1];
    const float* marker_x = (const float*)d_in[2];
    const float* Wf1      = (const float*)d_in[27];
    const float* bf1      = (const float*)d_in[28];
    const float* Wf2      = (const float*)d_in[29];
    const float* bf2      = (const float*)d_in[30];
    float* out = (float*)d_out;

    char* ws = (char*)d_ws;
    size_t off = 0;
    auto alloc = [&](size_t bytes) -> void* {
        void* p = ws + off;
        off = (off + bytes + 255) & ~(size_t)255;
        return p;
    };

    float* b1p_buf  = (float*)alloc(3 * 128 * sizeof(float));                 // zeroed
    float* pstat    = (float*)alloc((size_t)3 * SBLK * 2048 * sizeof(float)); // partials
    bf16*  w1t_buf  = (bf16*)alloc((size_t)3 * 32 * 1024 * 2);                // W1t per subnet
    float* a_buf[3], *h_buf[3];
    for (int i = 0; i < 3; i++) {
        a_buf[i] = (float*)alloc(1024 * 4);
        h_buf[i] = (float*)alloc((size_t)NB * 32 * 4);
    }
    bf16*  p1   = (bf16*)alloc((size_t)NB * KP * 2);
    bf16*  W2t  = (bf16*)alloc((size_t)NP * KP * 2);
    bf16*  S    = (bf16*)alloc((size_t)NB * NP * 2);

    SubP3 P;
    const float* xs[3] = {US_x, CDFI_x, marker_x};
    int Fs[3] = {1024, 1024, 10};
    for (int i = 0; i < 3; i++) {
        int base = 3 + i * 8;
        P.s[i].x     = xs[i];
        P.s[i].gamma = (const float*)d_in[base + 0];
        P.s[i].beta  = (const float*)d_in[base + 1];
        P.s[i].W1    = (const float*)d_in[base + 2];
        P.s[i].b1    = (const float*)d_in[base + 3];
        P.s[i].W2    = (const float*)d_in[base + 4];
        P.s[i].b2    = (const float*)d_in[base + 5];
        P.s[i].W3    = (const float*)d_in[base + 6];
        P.s[i].b3    = (const float*)d_in[base + 7];
        P.s[i].sum   = pstat + (size_t)i * SBLK * 2048;
        P.s[i].sumsq = pstat + (size_t)i * SBLK * 2048 + 1024;
        P.s[i].b1p   = b1p_buf + i * 128;
        P.s[i].a     = a_buf[i];
        P.s[i].hout  = h_buf[i];
        P.s[i].w1t   = w1t_buf + (size_t)i * 32 * 1024;
        P.s[i].F     = Fs[i];
    }

    float* us_h = h_buf[0];
    float* cd_h = h_buf[1];
    float* mk_h = h_buf[2];

    hipMemsetAsync(b1p_buf, 0, 3 * 128 * sizeof(float), stream);

    stats3_kernel<<<dim3(SBLK, 1, 3), 256, 0, stream>>>(P);
    prep3_kernel<<<dim3(32, 3), 256, 0, stream>>>(P);
    subnet3_kernel<<<dim3(256, 3), 256, 0, stream>>>(P);

    build_both<<<NB / 4 + 1089, 256, 0, stream>>>(mk_h, us_h, p1, Wf1, W2t);

    gemm_kernel<<<dim3(NB / 256, NP / 144), 512, 0, stream>>>(p1, W2t, S);

    epilogue_kernel<<<NB / 4, 256, 0, stream>>>(S, cd_h, bf1, Wf2, bf2, out);
}